// Round 7
// baseline (859.902 us; speedup 1.0000x reference)
//
#include <hip/hip_runtime.h>
#include <math.h>

#define LN_ 256      // ligand count L
#define PN_ 1024     // protein count P
#define DN_ 256      // model dim D
#define NH_ 4
#define RBF_N 50
#define NL_ 2
#define HD_ 64
#define EPSV 1e-5f
#define LP_ (LN_ * PN_)

typedef __attribute__((ext_vector_type(8))) short bf16x8;
typedef __attribute__((ext_vector_type(4))) float f32x4;

__device__ __forceinline__ float fast_sigmoid(float x){ return 1.f/(1.f+__expf(-x)); }
__device__ __forceinline__ float fast_silu(float x){ return x/(1.f+__expf(-x)); }
__device__ __forceinline__ short f2bf(float x){
  union { float f; unsigned u; } v; v.f = x;
  unsigned r = v.u + 0x7FFF + ((v.u >> 16) & 1);   // RNE
  return (short)(r >> 16);
}

// ---------------------------------------------------------------------------
// gemm8: 8 rows/block, 512 threads (k-split halves + LDS reduce).
// C[row,n] = act(dot(A[row,:K], W[:,n]) + b[n]); transOut: C[n*PN_+row].
// ---------------------------------------------------------------------------
struct GSeg {
  const float* A; const float* W; const float* bias; float* C;
  int K; int act; int transOut;
};
struct GArgs { GSeg s[3]; int b0, b1; };

__global__ __launch_bounds__(512) void gemm8(GArgs ga)
{
  extern __shared__ float sA[];   // 8 * K floats
  __shared__ float part_[2][8][256];
  int bid = blockIdx.x;
  int si = (bid < ga.b0) ? 0 : (bid < ga.b1 ? 1 : 2);
  int base = (si == 0) ? 0 : ((si == 1) ? ga.b0 : ga.b1);
  GSeg sg = ga.s[si];
  int row0 = (bid - base) * 8;
  int K = sg.K;
  int t = threadIdx.x;
  int col = t & 255, half = t >> 8;
  for (int idx = t; idx < 8 * K; idx += 512) {
    int r = idx / K, k = idx - r * K;
    sA[idx] = sg.A[(size_t)(row0 + r) * K + k];
  }
  __syncthreads();
  float acc[8];
  #pragma unroll
  for (int r = 0; r < 8; r++) acc[r] = 0.f;
  int K2 = K >> 1;
  for (int k = half * K2; k < half * K2 + K2; k++) {
    float w = sg.W[(size_t)k * DN_ + col];
    #pragma unroll
    for (int r = 0; r < 8; r++) acc[r] = fmaf(sA[r * K + k], w, acc[r]);
  }
  #pragma unroll
  for (int r = 0; r < 8; r++) part_[half][r][col] = acc[r];
  __syncthreads();
  if (half == 0) {
    float bv = sg.bias ? sg.bias[col] : 0.f;
    #pragma unroll
    for (int r = 0; r < 8; r++) {
      float v = part_[0][r][col] + part_[1][r][col] + bv;
      if (sg.act == 1) v = fast_silu(v);
      if (sg.transOut) sg.C[(size_t)col * PN_ + row0 + r] = v;
      else             sg.C[(size_t)(row0 + r) * DN_ + col] = v;
    }
  }
}

// ---------------------------------------------------------------------------
// rbf transpose: rbfT[k][idx] = rbf[idx][k].
// ---------------------------------------------------------------------------
__global__ __launch_bounds__(256) void rbf_transpose(
    const float* __restrict__ rbf, float* __restrict__ rbfT)
{
  __shared__ float ld[256][RBF_N + 1];
  int t = threadIdx.x;
  size_t base = (size_t)blockIdx.x << 8;
  const float* src = rbf + base * RBF_N;
  for (int i = 0; i < RBF_N; i++) {
    int fl = i * 256 + t;
    int row = fl / RBF_N, colk = fl - row * RBF_N;
    ld[row][colk] = src[fl];
  }
  __syncthreads();
  for (int k = 0; k < RBF_N; k++)
    rbfT[(size_t)k * LP_ + base + t] = ld[t][k];
}

// ---------------------------------------------------------------------------
// pack Wr (iw1 rbf-rows) into fragment-ready bf16 [d][64] (k>=50 zero).
// ---------------------------------------------------------------------------
__global__ __launch_bounds__(256) void wr_pack(
    const float* __restrict__ Wr, short* __restrict__ WT)
{
  int d = threadIdx.x;
  for (int k = 0; k < 64; k++)
    WT[d * 64 + k] = (k < RBF_N) ? f2bf(Wr[k * DN_ + d]) : (short)0;
}

// ---------------------------------------------------------------------------
// scores + rbf bias + softmax over P. 1024 threads, thread = p. grid = L.
// ---------------------------------------------------------------------------
__global__ __launch_bounds__(1024) void scores_softmax_l(
    const float* __restrict__ Q, const float* __restrict__ Kt,
    const float* __restrict__ rbfT, const float* __restrict__ rw,
    const float* __restrict__ rb, float* __restrict__ attn,
    float* __restrict__ amean)
{
  int l = blockIdx.x, t = threadIdx.x, lane = t & 63, wv = t >> 6;
  __shared__ float qs[DN_];
  __shared__ float rws[NH_][RBF_N];
  __shared__ float redm[NH_][16], reds[NH_][16];
  if (t < DN_) qs[t] = Q[(size_t)l * DN_ + t];
  if (t < RBF_N * NH_) rws[t & 3][t >> 2] = rw[t];
  __syncthreads();

  int p = t;
  size_t idx = ((size_t)l << 10) + p;
  float s2[NH_] = {0.f, 0.f, 0.f, 0.f};
  #pragma unroll 10
  for (int k = 0; k < RBF_N; k++) {
    float rv = rbfT[(size_t)k * LP_ + idx];
    s2[0] = fmaf(rv, rws[0][k], s2[0]);
    s2[1] = fmaf(rv, rws[1][k], s2[1]);
    s2[2] = fmaf(rv, rws[2][k], s2[2]);
    s2[3] = fmaf(rv, rws[3][k], s2[3]);
  }
  float sc[NH_];
  #pragma unroll
  for (int h = 0; h < NH_; h++) {
    const float* kp = Kt + ((size_t)(h << 6) << 10) + p;
    float a = 0.f;
    #pragma unroll 8
    for (int d = 0; d < HD_; d++) a = fmaf(qs[(h << 6) + d], kp[(size_t)d << 10], a);
    sc[h] = a * 0.125f + s2[h] + rb[h];
  }

  #pragma unroll
  for (int h = 0; h < NH_; h++) {
    float m = sc[h];
    for (int o = 32; o > 0; o >>= 1) m = fmaxf(m, __shfl_xor(m, o));
    if (lane == 0) redm[h][wv] = m;
  }
  __syncthreads();
  float mh[NH_];
  #pragma unroll
  for (int h = 0; h < NH_; h++) {
    float m = redm[h][0];
    for (int i = 1; i < 16; i++) m = fmaxf(m, redm[h][i]);
    mh[h] = m;
  }
  float e[NH_];
  #pragma unroll
  for (int h = 0; h < NH_; h++) {
    e[h] = __expf(sc[h] - mh[h]);
    float s = e[h];
    for (int o = 32; o > 0; o >>= 1) s += __shfl_xor(s, o);
    if (lane == 0) reds[h][wv] = s;
  }
  __syncthreads();
  float am = 0.f;
  #pragma unroll
  for (int h = 0; h < NH_; h++) {
    float s = reds[h][0];
    for (int i = 1; i < 16; i++) s += reds[h][i];
    float a = e[h] / s;
    attn[(((size_t)(l << 2) + h) << 10) + p] = a;
    am += a;
  }
  if (amean) amean[idx] = am * 0.25f;
}

// ---------------------------------------------------------------------------
// attend + proj + residual + LN, 1024 threads (p-split 4 ways). grid = L.
// All __syncthreads() at top level (no barrier inside divergent branches).
// ---------------------------------------------------------------------------
__global__ __launch_bounds__(1024) void attend_proj_ln(
    const float* __restrict__ attn, const float* __restrict__ V,
    const float* __restrict__ ow, const float* __restrict__ ob,
    const float* __restrict__ g, const float* __restrict__ bb,
    float* __restrict__ lig)
{
  int l = blockIdx.x, t = threadIdx.x;
  int q = t >> 8, col = t & 255, h = (t >> 6) & 3;
  __shared__ float part[4][256];
  __shared__ float as_[256];
  __shared__ float red[8];
  const float* aw = attn + (((size_t)(l << 2) + h) << 10);
  float acc = 0.f;
  for (int p = q * 256; p < q * 256 + 256; p++)
    acc = fmaf(aw[p], V[((size_t)p << 8) + col], acc);
  part[q][col] = acc;
  __syncthreads();
  if (t < 256) as_[t] = part[0][t] + part[1][t] + part[2][t] + part[3][t];
  __syncthreads();
  float acc2 = 0.f;
  for (int k = q * 64; k < q * 64 + 64; k++)
    acc2 = fmaf(as_[k], ow[(size_t)(k << 8) + col], acc2);
  part[q][col] = acc2;
  __syncthreads();
  // layernorm: first 256 threads hold data; barriers top-level
  float x = 0.f;
  if (t < 256)
    x = lig[((size_t)l << 8) + t] + ob[t]
      + part[0][t] + part[1][t] + part[2][t] + part[3][t];
  float sm = x;
  for (int o = 32; o > 0; o >>= 1) sm += __shfl_xor(sm, o);
  if (t < 256 && (t & 63) == 0) red[t >> 6] = sm;
  __syncthreads();
  float mu = (red[0] + red[1] + red[2] + red[3]) * (1.f / DN_);
  float dx = x - mu;
  float v = dx * dx;
  for (int o = 32; o > 0; o >>= 1) v += __shfl_xor(v, o);
  if (t < 256 && (t & 63) == 0) red[4 + (t >> 6)] = v;
  __syncthreads();
  if (t < 256) {
    float var = (red[4] + red[5] + red[6] + red[7]) * (1.f / DN_);
    lig[((size_t)l << 8) + t] = dx * (1.f / sqrtf(var + EPSV)) * g[t] + bb[t];
  }
}

// ---------------------------------------------------------------------------
// gate logits. grid = L, 128 threads.
// ---------------------------------------------------------------------------
__global__ __launch_bounds__(128) void gate_logits_k(
    const float* __restrict__ lig, const float* __restrict__ w1,
    const float* __restrict__ b1, const float* __restrict__ w2,
    const float* __restrict__ b2, float* __restrict__ glog)
{
  int l = blockIdx.x, n = threadIdx.x, lane = n & 63, wv = n >> 6;
  __shared__ float ls[DN_];
  __shared__ float red[2];
  ls[n] = lig[(size_t)l * DN_ + n];
  ls[n + 128] = lig[(size_t)l * DN_ + n + 128];
  __syncthreads();
  float acc = b1[n];
  #pragma unroll 4
  for (int k = 0; k < DN_; k++) acc = fmaf(ls[k], w1[k * 128 + n], acc);
  float part = tanhf(acc) * w2[n];
  for (int o = 32; o > 0; o >>= 1) part += __shfl_xor(part, o);
  if (lane == 0) red[wv] = part;
  __syncthreads();
  if (n == 0) glog[l] = red[0] + red[1] + b2[0];
}

// ---------------------------------------------------------------------------
// gate softmax + pooled repr + heads. 1 block, 256 threads.
// ---------------------------------------------------------------------------
__global__ __launch_bounds__(256) void pool_heads(
    const float* __restrict__ lig, const float* __restrict__ glog,
    const float* __restrict__ afw1, const float* __restrict__ afb1,
    const float* __restrict__ afw2, const float* __restrict__ afb2,
    const float* __restrict__ cfw1, const float* __restrict__ cfb1,
    const float* __restrict__ cfw2, const float* __restrict__ cfb2,
    float* __restrict__ out)
{
  __shared__ float wsh[LN_];
  __shared__ float cr[DN_];
  __shared__ float h1s[DN_];
  __shared__ float h2s[128];
  __shared__ float red[8];
  int t = threadIdx.x, lane = t & 63, wv = t >> 6;
  float x = glog[t];
  float m = x;
  for (int o = 32; o > 0; o >>= 1) m = fmaxf(m, __shfl_xor(m, o));
  if (lane == 0) red[wv] = m;
  __syncthreads();
  m = fmaxf(fmaxf(red[0], red[1]), fmaxf(red[2], red[3]));
  float e = __expf(x - m);
  float s = e;
  for (int o = 32; o > 0; o >>= 1) s += __shfl_xor(s, o);
  if (lane == 0) red[4 + wv] = s;
  __syncthreads();
  s = red[4] + red[5] + red[6] + red[7];
  wsh[t] = e / s;
  __syncthreads();
  float acc = 0.f;
  #pragma unroll 4
  for (int l2 = 0; l2 < LN_; l2++) acc = fmaf(wsh[l2], lig[(size_t)l2 * DN_ + t], acc);
  cr[t] = acc;
  __syncthreads();
  float a = afb1[t];
  #pragma unroll 4
  for (int d = 0; d < DN_; d++) a = fmaf(cr[d], afw1[d * DN_ + t], a);
  h1s[t] = fast_silu(a);
  if (t < 128) {
    float c = cfb1[t];
    #pragma unroll 4
    for (int d = 0; d < DN_; d++) c = fmaf(cr[d], cfw1[d * 128 + t], c);
    h2s[t] = fast_silu(c);
  }
  __syncthreads();
  float pp = h1s[t] * afw2[t];
  for (int o = 32; o > 0; o >>= 1) pp += __shfl_xor(pp, o);
  if (lane == 0) red[wv] = pp;
  float cp = (t < 128) ? h2s[t] * cfw2[t] : 0.f;
  for (int o = 32; o > 0; o >>= 1) cp += __shfl_xor(cp, o);
  if (lane == 0) red[4 + wv] = cp;
  __syncthreads();
  if (t == 0) {
    float pkd = red[0] + red[1] + red[2] + red[3] + afb2[0];
    float cl  = red[4] + red[5] + red[6] + red[7] + cfb2[0];
    float conf = fast_sigmoid(cl);
    out[0] = pkd * conf;
    out[1] = pkd;
    out[2] = conf;
  }
}

// ---------------------------------------------------------------------------
// pair head v3: MFMA for the rank-50 term.
// H[p,d] = A[l,d] + B[p,d] + sum_k rbf[lp,k] Wr[k,d]; imap = sigmoid(silu(H)@w2+ib2)
// block = 1 l x 256 p (grid 1024), 512 threads = 8 waves, 16x16x32 bf16 MFMA.
// Fragment layouts per learn_hip m89: A row=lane&15,k=(lane>>4)*8+j;
// B col=lane&15,k=(lane>>4)*8+j; D col=lane&15,row=(lane>>4)*4+reg.
// ---------------------------------------------------------------------------
#define RSTR 72      // R_lds row stride in bf16 (144 B, 16B-aligned)
#define BTP 261      // sBT row stride in floats (261 mod 32 = 5, odd -> spread)
__global__ __launch_bounds__(512) void pair_main3(
    const float* __restrict__ A, const float* __restrict__ BT,
    const float* __restrict__ rbf, const short* __restrict__ WT,
    const float* __restrict__ w2, const float* __restrict__ ib2,
    float* __restrict__ imap)
{
  __shared__ short R_lds[256 * RSTR];     // 36864 B
  __shared__ float sBT[16 * BTP];         // 16704 B
  __shared__ float sw2[DN_ * 5];          // 5120 B
  __shared__ float sAl[DN_];              // 1024 B

  int t = threadIdx.x;
  int lane = t & 63, wid = t >> 6;
  int bid = blockIdx.x;
  int l = bid >> 2;
  int p0 = (bid & 3) << 8;

  // zero R_lds (covers k-padding 50..63)
  {
    unsigned* rz = (unsigned*)R_lds;
    #pragma unroll
    for (int i = 0; i < 18; i++) rz[t + i * 512] = 0u;
  }
  __syncthreads();
  // stage rbf rows -> bf16 (flat coalesced read)
  {
    const float* src = rbf + ((size_t)(l << 10) + p0) * RBF_N;
    #pragma unroll
    for (int i = 0; i < 25; i++) {
      int idx = t + i * 512;                 // 0..12799
      int row = idx / RBF_N, k = idx - row * RBF_N;
      R_lds[row * RSTR + k] = f2bf(src[idx]);
    }
  }
  // stage w2 and A row
  for (int i = t; i < DN_ * 5; i += 512) sw2[i] = w2[i];
  if (t < DN_) sAl[t] = A[((size_t)l << 8) + t];
  __syncthreads();

  // A-fragments for this wave's two ptiles (k-slices ks=0,1)
  int m = lane & 15, gq = lane >> 4;
  int pt0 = wid * 2, pt1 = wid * 2 + 1;
  bf16x8 a00 = *(const bf16x8*)&R_lds[(pt0 * 16 + m) * RSTR + 0 * 32 + gq * 8];
  bf16x8 a01 = *(const bf16x8*)&R_lds[(pt0 * 16 + m) * RSTR + 1 * 32 + gq * 8];
  bf16x8 a10 = *(const bf16x8*)&R_lds[(pt1 * 16 + m) * RSTR + 0 * 32 + gq * 8];
  bf16x8 a11 = *(const bf16x8*)&R_lds[(pt1 * 16 + m) * RSTR + 1 * 32 + gq * 8];

  float acc5[2][4][5];
  #pragma unroll
  for (int i = 0; i < 2; i++)
    #pragma unroll
    for (int r = 0; r < 4; r++)
      #pragma unroll
      for (int o = 0; o < 5; o++) acc5[i][r][o] = 0.f;

  for (int nt = 0; nt < 16; nt++) {
    __syncthreads();
    // stage sBT[16 d][256 p]
    #pragma unroll
    for (int i = 0; i < 8; i++) {
      int idx = t + i * 512;
      int row = idx >> 8, colp = idx & 255;
      sBT[row * BTP + colp] = BT[(size_t)((nt * 16 + row) << 10) + p0 + colp];
    }
    __syncthreads();

    // B-fragments from global packed WT [d][64]
    int n = nt * 16 + m;
    bf16x8 b0 = *(const bf16x8*)&WT[n * 64 + 0 * 32 + gq * 8];
    bf16x8 b1 = *(const bf16x8*)&WT[n * 64 + 1 * 32 + gq * 8];

    float bA = sAl[n];
    #pragma unroll
    for (int pi = 0; pi < 2; pi++) {
      f32x4 acc = {0.f, 0.f, 0.f, 0.f};
      if (pi == 0) {
        acc = __builtin_amdgcn_mfma_f32_16x16x32_bf16(a00, b0, acc, 0, 0, 0);
        acc = __builtin_amdgcn_mfma_f32_16x16x32_bf16(a01, b1, acc, 0, 0, 0);
      } else {
        acc = __builtin_amdgcn_mfma_f32_16x16x32_bf16(a10, b0, acc, 0, 0, 0);
        acc = __builtin_amdgcn_mfma_f32_16x16x32_bf16(a11, b1, acc, 0, 0, 0);
      }
      int ptb = (pi == 0 ? pt0 : pt1) * 16 + gq * 4;
      #pragma unroll
      for (int r = 0; r < 4; r++) {
        float bB = sBT[m * BTP + ptb + r];
        float h = acc[r] + bA + bB;
        float sh = fast_silu(h);
        #pragma unroll
        for (int o = 0; o < 5; o++)
          acc5[pi][r][o] = fmaf(sh, sw2[n * 5 + o], acc5[pi][r][o]);
      }
    }
  }

  // reduce over the 16 d-lanes (lane&15), butterfly
  #pragma unroll
  for (int i = 0; i < 2; i++)
    #pragma unroll
    for (int r = 0; r < 4; r++)
      #pragma unroll
      for (int o = 0; o < 5; o++) {
        float v = acc5[i][r][o];
        v += __shfl_xor(v, 1);
        v += __shfl_xor(v, 2);
        v += __shfl_xor(v, 4);
        v += __shfl_xor(v, 8);
        acc5[i][r][o] = v;
      }

  // write: lanes with (lane&15) < 5 write output o = lane&15
  if (m < 5) {
    float bo = ib2[m];
    #pragma unroll
    for (int pi = 0; pi < 2; pi++) {
      int ptb = (pi == 0 ? pt0 : pt1) * 16 + gq * 4;
      #pragma unroll
      for (int r = 0; r < 4; r++) {
        float v = 0.f;
        #pragma unroll
        for (int o = 0; o < 5; o++) if (m == o) v = acc5[pi][r][o];
        int p = p0 + ptb + r;
        imap[((size_t)(l << 10) + p) * 5 + m] = fast_sigmoid(v + bo);
      }
    }
  }
}

// ---------------------------------------------------------------------------
extern "C" void kernel_launch(void* const* d_in, const int* in_sizes, int n_in,
                              void* d_out, int out_size, void* d_ws, size_t ws_size,
                              hipStream_t stream)
{
  const float* pf    = (const float*)d_in[0];
  const float* lf    = (const float*)d_in[1];
  const float* rbf   = (const float*)d_in[4];
  const float* pe_w1 = (const float*)d_in[5];
  const float* pe_b1 = (const float*)d_in[6];
  const float* pe_w2 = (const float*)d_in[7];
  const float* pe_b2 = (const float*)d_in[8];
  const float* le_w1 = (const float*)d_in[9];
  const float* le_b1 = (const float*)d_in[10];
  const float* le_w2 = (const float*)d_in[11];
  const float* le_b2 = (const float*)d_in[12];
  const float* qw = (const float*)d_in[13];
  const float* qb = (const float*)d_in[14];
  const float* kw = (const float*)d_in[15];
  const float* kb = (const float*)d_in[16];
  const float* vw = (const float*)d_in[17];
  const float* vb = (const float*)d_in[18];
  const float* rw = (const float*)d_in[19];
  const float* rb = (const float*)d_in[20];
  const float* ow = (const float*)d_in[21];
  const float* ob = (const float*)d_in[22];
  const float* ln_g = (const float*)d_in[23];
  const float* ln_b = (const float*)d_in[24];
  const float* pg_w1 = (const float*)d_in[25];
  const float* pg_b1 = (const float*)d_in[26];
  const float* pg_w2 = (const float*)d_in[27];
  const float* pg_b2 = (const float*)d_in[28];
  const float* af_w1 = (const float*)d_in[29];
  const float* af_b1 = (const float*)d_in[30];
  const float* af_w2 = (const float*)d_in[31];
  const float* af_b2 = (const float*)d_in[32];
  const float* cf_w1 = (const float*)d_in[33];
  const float* cf_b1 = (const float*)d_in[34];
  const float* cf_w2 = (const float*)d_in[35];
  const float* cf_b2 = (const float*)d_in[36];
  const float* iw1 = (const float*)d_in[37];
  const float* ib1 = (const float*)d_in[38];
  const float* iw2 = (const float*)d_in[39];
  const float* ib2 = (const float*)d_in[40];

  float* out = (float*)d_out;

  // workspace layout (floats)
  float* w = (float*)d_ws;
  size_t off = 0;
  float* prot_h = w + off; off += (size_t)PN_ * DN_;
  float* lig_h  = w + off; off += (size_t)LN_ * DN_;
  float* ph1    = w + off; off += (size_t)PN_ * DN_;
  float* lh1    = w + off; off += (size_t)LN_ * DN_;
  float* Qb     = w + off; off += (size_t)LN_ * DN_;
  float* Kt     = w + off; off += (size_t)DN_ * PN_;   // K^T; reused as pairBT
  float* Vb     = w + off; off += (size_t)PN_ * DN_;
  float* attn   = w + off; off += (size_t)LN_ * NH_ * PN_;
  float* pairA  = w + off; off += (size_t)LN_ * DN_;
  float* glog   = w + off; off += LN_;
  off = (off + 255) & ~(size_t)255;
  float* WrBF   = w + off; off += (size_t)DN_ * 64 / 2;  // 256x64 bf16
  off = (off + 255) & ~(size_t)255;
  float* rbfT   = w + off; off += (size_t)RBF_N * LP_;   // 52.4 MB

  const int PB = PN_ / 8;   // 128
  const int LB = LN_ / 8;   // 32
  const size_t smax = 8 * DN_ * sizeof(float);

  rbf_transpose<<<LP_ / 256, 256, 0, stream>>>(rbf, rbfT);
  wr_pack<<<1, 256, 0, stream>>>(iw1 + (size_t)2 * DN_ * DN_, (short*)WrBF);

  // encoder stage 1
  {
    GArgs ga;
    ga.s[0] = { pf, pe_w1, pe_b1, ph1, 20, 1, 0 };
    ga.s[1] = { lf, le_w1, le_b1, lh1, 20, 1, 0 };
    ga.s[2] = ga.s[1];
    ga.b0 = PB; ga.b1 = PB + LB;
    gemm8<<<PB + LB, 512, smax, stream>>>(ga);
  }
  // encoder stage 2
  {
    GArgs ga;
    ga.s[0] = { ph1, pe_w2, pe_b2, prot_h, DN_, 0, 0 };
    ga.s[1] = { lh1, le_w2, le_b2, lig_h, DN_, 0, 0 };
    ga.s[2] = ga.s[1];
    ga.b0 = PB; ga.b1 = PB + LB;
    gemm8<<<PB + LB, 512, smax, stream>>>(ga);
  }

  // cross-attention layers
  for (int i = 0; i < NL_; i++) {
    const size_t wo = (size_t)i * DN_ * DN_;
    {
      GArgs ga;
      ga.s[0] = { lig_h,  qw + wo, qb + i * DN_, Qb, DN_, 0, 0 };
      ga.s[1] = { prot_h, kw + wo, kb + i * DN_, Kt, DN_, 0, 1 };  // K^T
      ga.s[2] = { prot_h, vw + wo, vb + i * DN_, Vb, DN_, 0, 0 };
      ga.b0 = LB; ga.b1 = LB + PB;
      gemm8<<<LB + 2 * PB, 512, smax, stream>>>(ga);
    }
    scores_softmax_l<<<LN_, 1024, 0, stream>>>(
        Qb, Kt, rbfT, rw + (size_t)i * RBF_N * NH_, rb + i * NH_, attn,
        (i == NL_ - 1) ? (out + 3 + (size_t)LN_ * PN_ * 5) : nullptr);
    attend_proj_ln<<<LN_, 1024, 0, stream>>>(attn, Vb, ow + wo, ob + i * DN_,
                                             ln_g + i * DN_, ln_b + i * DN_, lig_h);
  }

  // gated pooling + heads
  gate_logits_k<<<LN_, 128, 0, stream>>>(lig_h, pg_w1, pg_b1, pg_w2, pg_b2, glog);
  pool_heads<<<1, 256, 0, stream>>>(lig_h, glog, af_w1, af_b1, af_w2, af_b2,
                                    cf_w1, cf_b1, cf_w2, cf_b2, out);

  // pair head precompute: pairA = lig_h@iw1[0:256]+ib1 (rows),
  // pairBT = (prot_h@iw1[256:512])^T via transOut (reuses Kt)
  {
    GArgs ga;
    ga.s[0] = { lig_h,  iw1,                       ib1,     pairA, DN_, 0, 0 };
    ga.s[1] = { prot_h, iw1 + (size_t)DN_ * DN_,   nullptr, Kt,    DN_, 0, 1 };
    ga.s[2] = ga.s[1];
    ga.b0 = LB; ga.b1 = LB + PB;
    gemm8<<<LB + PB, 512, smax, stream>>>(ga);
  }

  // fused pair head v3 (MFMA)
  pair_main3<<<LP_ / 256, 512, 0, stream>>>(
      pairA, Kt, rbf, (const short*)WrBF, iw2, ib2, out + 3);
}

// Round 8
// 715.171 us; speedup vs baseline: 1.2024x; 1.2024x over previous
//
#include <hip/hip_runtime.h>
#include <math.h>

#define LN_ 256      // ligand count L
#define PN_ 1024     // protein count P
#define DN_ 256      // model dim D
#define NH_ 4
#define RBF_N 50
#define NL_ 2
#define HD_ 64
#define EPSV 1e-5f
#define LP_ (LN_ * PN_)

typedef __attribute__((ext_vector_type(8))) short bf16x8;
typedef __attribute__((ext_vector_type(4))) float f32x4;

__device__ __forceinline__ float fast_sigmoid(float x){ return 1.f/(1.f+__expf(-x)); }
__device__ __forceinline__ float fast_silu(float x){ return x/(1.f+__expf(-x)); }
__device__ __forceinline__ short f2bf(float x){
  union { float f; unsigned u; } v; v.f = x;
  unsigned r = v.u + 0x7FFF + ((v.u >> 16) & 1);   // RNE
  return (short)(r >> 16);
}

// ---------------------------------------------------------------------------
// gemm8 (r4-measured form): C[row,n] = act(dot(A[row,:K], W[:,n]) + b[n]),
// 8 rows/block, 256 threads, up to 3 segments. transOut: C[n*PN_+row].
// ---------------------------------------------------------------------------
struct GSeg {
  const float* A; const float* W; const float* bias; float* C;
  int K; int act; int transOut;
};
struct GArgs { GSeg s[3]; int b0, b1; };

__global__ __launch_bounds__(256) void gemm8(GArgs ga)
{
  extern __shared__ float sA[];   // 8 * K floats
  int bid = blockIdx.x;
  int si = (bid < ga.b0) ? 0 : (bid < ga.b1 ? 1 : 2);
  int base = (si == 0) ? 0 : ((si == 1) ? ga.b0 : ga.b1);
  GSeg sg = ga.s[si];
  int row0 = (bid - base) * 8;
  int K = sg.K;
  int t = threadIdx.x;
  for (int idx = t; idx < 8 * K; idx += 256) {
    int r = idx / K, k = idx - r * K;
    sA[idx] = sg.A[(size_t)(row0 + r) * K + k];
  }
  __syncthreads();
  float acc[8];
  float bv = sg.bias ? sg.bias[t] : 0.f;
  #pragma unroll
  for (int r = 0; r < 8; r++) acc[r] = bv;
  for (int k = 0; k < K; k++) {
    float w = sg.W[(size_t)k * DN_ + t];
    #pragma unroll
    for (int r = 0; r < 8; r++) acc[r] = fmaf(sA[r * K + k], w, acc[r]);
  }
  #pragma unroll
  for (int r = 0; r < 8; r++) {
    float v = acc[r];
    if (sg.act == 1) v = fast_silu(v);
    if (sg.transOut) sg.C[(size_t)t * PN_ + row0 + r] = v;
    else             sg.C[(size_t)(row0 + r) * DN_ + t] = v;
  }
}

// ---------------------------------------------------------------------------
// rbf transpose: rbfT[k][idx] = rbf[idx][k].
// ---------------------------------------------------------------------------
__global__ __launch_bounds__(256) void rbf_transpose(
    const float* __restrict__ rbf, float* __restrict__ rbfT)
{
  __shared__ float ld[256][RBF_N + 1];
  int t = threadIdx.x;
  size_t base = (size_t)blockIdx.x << 8;
  const float* src = rbf + base * RBF_N;
  for (int i = 0; i < RBF_N; i++) {
    int fl = i * 256 + t;
    int row = fl / RBF_N, colk = fl - row * RBF_N;
    ld[row][colk] = src[fl];
  }
  __syncthreads();
  for (int k = 0; k < RBF_N; k++)
    rbfT[(size_t)k * LP_ + base + t] = ld[t][k];
}

// ---------------------------------------------------------------------------
// pack Wr into fragment-ready bf16 [d][64] (k>=50 zero).
// ---------------------------------------------------------------------------
__global__ __launch_bounds__(256) void wr_pack(
    const float* __restrict__ Wr, short* __restrict__ WT)
{
  int d = threadIdx.x;
  for (int k = 0; k < 64; k++)
    WT[d * 64 + k] = (k < RBF_N) ? f2bf(Wr[k * DN_ + d]) : (short)0;
}

// ---------------------------------------------------------------------------
// scores + rbf bias + softmax over P (r4-measured form). grid = L, 256 thr.
// ---------------------------------------------------------------------------
__global__ __launch_bounds__(256) void scores_softmax_l(
    const float* __restrict__ Q, const float* __restrict__ Kt,
    const float* __restrict__ rbfT, const float* __restrict__ rw,
    const float* __restrict__ rb, float* __restrict__ attn,
    float* __restrict__ amean)
{
  int l = blockIdx.x, t = threadIdx.x, lane = t & 63, wv = t >> 6;
  __shared__ float qs[DN_];
  __shared__ float rws[NH_][RBF_N];
  __shared__ float redm[16], reds[16];
  qs[t] = Q[(size_t)l * DN_ + t];
  if (t < RBF_N * NH_) rws[t & 3][t >> 2] = rw[t];
  __syncthreads();

  float sc[NH_][4];
  for (int i = 0; i < 4; i++) {
    int p = t + (i << 8);
    size_t idx = ((size_t)l << 10) + p;
    float s2[NH_] = {0.f, 0.f, 0.f, 0.f};
    #pragma unroll 10
    for (int k = 0; k < RBF_N; k++) {
      float rv = rbfT[(size_t)k * LP_ + idx];
      s2[0] = fmaf(rv, rws[0][k], s2[0]);
      s2[1] = fmaf(rv, rws[1][k], s2[1]);
      s2[2] = fmaf(rv, rws[2][k], s2[2]);
      s2[3] = fmaf(rv, rws[3][k], s2[3]);
    }
    #pragma unroll
    for (int h = 0; h < NH_; h++) {
      const float* kp = Kt + ((size_t)(h << 6) << 10) + p;
      float a = 0.f;
      #pragma unroll 8
      for (int d = 0; d < HD_; d++) a = fmaf(qs[(h << 6) + d], kp[(size_t)d << 10], a);
      sc[h][i] = a * 0.125f + s2[h] + rb[h];
    }
  }

  float mh[NH_];
  #pragma unroll
  for (int h = 0; h < NH_; h++) {
    float m = fmaxf(fmaxf(sc[h][0], sc[h][1]), fmaxf(sc[h][2], sc[h][3]));
    for (int o = 32; o > 0; o >>= 1) m = fmaxf(m, __shfl_xor(m, o));
    if (lane == 0) redm[h * 4 + wv] = m;
  }
  __syncthreads();
  #pragma unroll
  for (int h = 0; h < NH_; h++)
    mh[h] = fmaxf(fmaxf(redm[h * 4 + 0], redm[h * 4 + 1]),
                  fmaxf(redm[h * 4 + 2], redm[h * 4 + 3]));

  float e[NH_][4], inv[NH_];
  #pragma unroll
  for (int h = 0; h < NH_; h++) {
    float s = 0.f;
    #pragma unroll
    for (int i = 0; i < 4; i++) { e[h][i] = __expf(sc[h][i] - mh[h]); s += e[h][i]; }
    for (int o = 32; o > 0; o >>= 1) s += __shfl_xor(s, o);
    if (lane == 0) reds[h * 4 + wv] = s;
  }
  __syncthreads();
  #pragma unroll
  for (int h = 0; h < NH_; h++)
    inv[h] = 1.f / (reds[h * 4 + 0] + reds[h * 4 + 1] + reds[h * 4 + 2] + reds[h * 4 + 3]);

  #pragma unroll
  for (int h = 0; h < NH_; h++)
    for (int i = 0; i < 4; i++)
      attn[(((size_t)(l << 2) + h) << 10) + t + (i << 8)] = e[h][i] * inv[h];

  if (amean) {
    for (int i = 0; i < 4; i++) {
      float s = e[0][i] * inv[0] + e[1][i] * inv[1] + e[2][i] * inv[2] + e[3][i] * inv[3];
      amean[((size_t)l << 10) + t + (i << 8)] = s * 0.25f;
    }
  }
}

// ---------------------------------------------------------------------------
// attend + proj + residual + LN (r4-measured form). grid = L, 256 thr.
// ---------------------------------------------------------------------------
__global__ __launch_bounds__(256) void attend_proj_ln(
    const float* __restrict__ attn, const float* __restrict__ V,
    const float* __restrict__ ow, const float* __restrict__ ob,
    const float* __restrict__ g, const float* __restrict__ bb,
    float* __restrict__ lig)
{
  int l = blockIdx.x, t = threadIdx.x, lane = t & 63, wv = t >> 6;
  int h = t >> 6, d = t & 63;
  __shared__ float as[DN_];
  __shared__ float red[8];
  const float* aw = attn + (((size_t)(l << 2) + h) << 10);
  const float* Vp = V + (h << 6) + d;
  float acc = 0.f;
  #pragma unroll 8
  for (int p = 0; p < PN_; p++) acc = fmaf(aw[p], Vp[(size_t)p << 8], acc);
  as[t] = acc;
  __syncthreads();
  float acc2 = ob[t];
  #pragma unroll 4
  for (int k = 0; k < DN_; k++) acc2 = fmaf(as[k], ow[(size_t)(k << 8) + t], acc2);
  float x = lig[((size_t)l << 8) + t] + acc2;
  float sm = x;
  for (int o = 32; o > 0; o >>= 1) sm += __shfl_xor(sm, o);
  if (lane == 0) red[wv] = sm;
  __syncthreads();
  float mu = (red[0] + red[1] + red[2] + red[3]) * (1.f / DN_);
  float dx = x - mu;
  float v = dx * dx;
  for (int o = 32; o > 0; o >>= 1) v += __shfl_xor(v, o);
  if (lane == 0) red[4 + wv] = v;
  __syncthreads();
  float var = (red[4] + red[5] + red[6] + red[7]) * (1.f / DN_);
  lig[((size_t)l << 8) + t] = dx * (1.f / sqrtf(var + EPSV)) * g[t] + bb[t];
}

// ---------------------------------------------------------------------------
// gate logits. grid = L, 128 threads.
// ---------------------------------------------------------------------------
__global__ __launch_bounds__(128) void gate_logits_k(
    const float* __restrict__ lig, const float* __restrict__ w1,
    const float* __restrict__ b1, const float* __restrict__ w2,
    const float* __restrict__ b2, float* __restrict__ glog)
{
  int l = blockIdx.x, n = threadIdx.x, lane = n & 63, wv = n >> 6;
  __shared__ float ls[DN_];
  __shared__ float red[2];
  ls[n] = lig[(size_t)l * DN_ + n];
  ls[n + 128] = lig[(size_t)l * DN_ + n + 128];
  __syncthreads();
  float acc = b1[n];
  #pragma unroll 4
  for (int k = 0; k < DN_; k++) acc = fmaf(ls[k], w1[k * 128 + n], acc);
  float part = tanhf(acc) * w2[n];
  for (int o = 32; o > 0; o >>= 1) part += __shfl_xor(part, o);
  if (lane == 0) red[wv] = part;
  __syncthreads();
  if (n == 0) glog[l] = red[0] + red[1] + b2[0];
}

// ---------------------------------------------------------------------------
// gate softmax + pooled repr + heads. 1 block, 256 threads.
// ---------------------------------------------------------------------------
__global__ __launch_bounds__(256) void pool_heads(
    const float* __restrict__ lig, const float* __restrict__ glog,
    const float* __restrict__ afw1, const float* __restrict__ afb1,
    const float* __restrict__ afw2, const float* __restrict__ afb2,
    const float* __restrict__ cfw1, const float* __restrict__ cfb1,
    const float* __restrict__ cfw2, const float* __restrict__ cfb2,
    float* __restrict__ out)
{
  __shared__ float wsh[LN_];
  __shared__ float cr[DN_];
  __shared__ float h1s[DN_];
  __shared__ float h2s[128];
  __shared__ float red[8];
  int t = threadIdx.x, lane = t & 63, wv = t >> 6;
  float x = glog[t];
  float m = x;
  for (int o = 32; o > 0; o >>= 1) m = fmaxf(m, __shfl_xor(m, o));
  if (lane == 0) red[wv] = m;
  __syncthreads();
  m = fmaxf(fmaxf(red[0], red[1]), fmaxf(red[2], red[3]));
  float e = __expf(x - m);
  float s = e;
  for (int o = 32; o > 0; o >>= 1) s += __shfl_xor(s, o);
  if (lane == 0) red[4 + wv] = s;
  __syncthreads();
  s = red[4] + red[5] + red[6] + red[7];
  wsh[t] = e / s;
  __syncthreads();
  float acc = 0.f;
  #pragma unroll 4
  for (int l2 = 0; l2 < LN_; l2++) acc = fmaf(wsh[l2], lig[(size_t)l2 * DN_ + t], acc);
  cr[t] = acc;
  __syncthreads();
  float a = afb1[t];
  #pragma unroll 4
  for (int d = 0; d < DN_; d++) a = fmaf(cr[d], afw1[d * DN_ + t], a);
  h1s[t] = fast_silu(a);
  if (t < 128) {
    float c = cfb1[t];
    #pragma unroll 4
    for (int d = 0; d < DN_; d++) c = fmaf(cr[d], cfw1[d * 128 + t], c);
    h2s[t] = fast_silu(c);
  }
  __syncthreads();
  float pp = h1s[t] * afw2[t];
  for (int o = 32; o > 0; o >>= 1) pp += __shfl_xor(pp, o);
  if (lane == 0) red[wv] = pp;
  float cp = (t < 128) ? h2s[t] * cfw2[t] : 0.f;
  for (int o = 32; o > 0; o >>= 1) cp += __shfl_xor(cp, o);
  if (lane == 0) red[4 + wv] = cp;
  __syncthreads();
  if (t == 0) {
    float pkd = red[0] + red[1] + red[2] + red[3] + afb2[0];
    float cl  = red[4] + red[5] + red[6] + red[7] + cfb2[0];
    float conf = fast_sigmoid(cl);
    out[0] = pkd * conf;
    out[1] = pkd;
    out[2] = conf;
  }
}

// ---------------------------------------------------------------------------
// pair head v4: MFMA + double-buffered sBT overlaid on dead R region (union),
// T14 async-stage. block = 1 l x 128 p, 512 thr = 8 waves (1 ptile/wave).
// grid = 2048. LDS 24.6KB -> ~3 blocks/CU.
// ---------------------------------------------------------------------------
#define RSTR 72      // R rows stride in bf16
#define BTP2 133     // sBT row stride in floats (133%32=5 -> spread banks)
union PairSMem {
  short R[128 * RSTR];          // 18432 B (dead after frag extraction)
  float B[2][16 * BTP2];        // 17024 B (double-buffered B tile)
};
__global__ __launch_bounds__(512, 6) void pair_main4(
    const float* __restrict__ A, const float* __restrict__ BT,
    const float* __restrict__ rbf, const short* __restrict__ WT,
    const float* __restrict__ w2, const float* __restrict__ ib2,
    float* __restrict__ imap)
{
  __shared__ PairSMem u;
  __shared__ float sw2[DN_ * 5];
  __shared__ float sAl[DN_];

  int t = threadIdx.x;
  int lane = t & 63, wid = t >> 6;
  int bid = blockIdx.x;
  int l = bid >> 3;
  int p0 = (bid & 7) << 7;          // 128-p tile

  // --- stage rbf rows -> bf16 R (zero-padded k 50..63) ---
  {
    unsigned* rz = (unsigned*)u.R;
    #pragma unroll
    for (int i = 0; i < 9; i++) rz[t + i * 512] = 0u;   // 4608 u32 = 128*72 shorts
  }
  __syncthreads();
  {
    const float* src = rbf + ((size_t)(l << 10) + p0) * RBF_N;
    #pragma unroll
    for (int i = 0; i < 13; i++) {
      int idx = t + i * 512;                 // 0..6655, need <6400
      if (idx < 128 * RBF_N) {
        int row = idx / RBF_N, k = idx - row * RBF_N;
        u.R[row * RSTR + k] = f2bf(src[idx]);
      }
    }
  }
  for (int i = t; i < DN_ * 5; i += 512) sw2[i] = w2[i];
  if (t < DN_) sAl[t] = A[((size_t)l << 8) + t];
  __syncthreads();

  // --- extract A-fragments (wave wid owns local rows wid*16..wid*16+15) ---
  int m = lane & 15, gq = lane >> 4;
  bf16x8 a0 = *(const bf16x8*)&u.R[(wid * 16 + m) * RSTR + 0 + gq * 8];
  bf16x8 a1 = *(const bf16x8*)&u.R[(wid * 16 + m) * RSTR + 32 + gq * 8];
  __syncthreads();   // all waves done reading R before B overwrites it

  // --- prologue: stage B tile nt=0 into buf 0 ---
  int srow = t >> 7, scol = t & 127;
  #pragma unroll
  for (int i = 0; i < 4; i++)
    u.B[0][(srow + 4 * i) * BTP2 + scol] =
        BT[(size_t)(srow + 4 * i) * PN_ + p0 + scol];
  __syncthreads();

  float acc5[4][5];
  #pragma unroll
  for (int r = 0; r < 4; r++)
    #pragma unroll
    for (int o = 0; o < 5; o++) acc5[r][o] = 0.f;

  int cur = 0;
  for (int nt = 0; nt < 16; nt++) {
    // issue next-tile loads early (T14): latency hides under compute
    float ld0 = 0.f, ld1 = 0.f, ld2 = 0.f, ld3 = 0.f;
    if (nt < 15) {
      const float* bsrc = BT + (size_t)((nt + 1) * 16 + srow) * PN_ + p0 + scol;
      ld0 = bsrc[0];
      ld1 = bsrc[(size_t)4 * PN_];
      ld2 = bsrc[(size_t)8 * PN_];
      ld3 = bsrc[(size_t)12 * PN_];
    }

    // compute tile nt
    int n = nt * 16 + m;
    bf16x8 b0 = *(const bf16x8*)&WT[n * 64 + gq * 8];
    bf16x8 b1 = *(const bf16x8*)&WT[n * 64 + 32 + gq * 8];
    f32x4 acc = {0.f, 0.f, 0.f, 0.f};
    acc = __builtin_amdgcn_mfma_f32_16x16x32_bf16(a0, b0, acc, 0, 0, 0);
    acc = __builtin_amdgcn_mfma_f32_16x16x32_bf16(a1, b1, acc, 0, 0, 0);
    float bA = sAl[n];
    const float* bp = &u.B[cur][m * BTP2 + wid * 16 + gq * 4];
    #pragma unroll
    for (int r = 0; r < 4; r++) {
      float h = acc[r] + bA + bp[r];
      float sh = fast_silu(h);
      #pragma unroll
      for (int o = 0; o < 5; o++)
        acc5[r][o] = fmaf(sh, sw2[n * 5 + o], acc5[r][o]);
    }
    __syncthreads();
    if (nt < 15) {
      float* bd = &u.B[cur ^ 1][srow * BTP2 + scol];
      bd[0 * 4 * BTP2] = ld0;
      bd[1 * 4 * BTP2] = ld1;
      bd[2 * 4 * BTP2] = ld2;
      bd[3 * 4 * BTP2] = ld3;
      __syncthreads();
      cur ^= 1;
    }
  }

  // butterfly-reduce over the 16 d-lanes (lane bits 0..3)
  #pragma unroll
  for (int r = 0; r < 4; r++)
    #pragma unroll
    for (int o = 0; o < 5; o++) {
      float v = acc5[r][o];
      v += __shfl_xor(v, 1);
      v += __shfl_xor(v, 2);
      v += __shfl_xor(v, 4);
      v += __shfl_xor(v, 8);
      acc5[r][o] = v;
    }

  if (m < 5) {
    float bo = ib2[m];
    #pragma unroll
    for (int r = 0; r < 4; r++) {
      float v = 0.f;
      #pragma unroll
      for (int o = 0; o < 5; o++) if (m == o) v = acc5[r][o];
      int p = p0 + wid * 16 + gq * 4 + r;
      imap[((size_t)(l << 10) + p) * 5 + m] = fast_sigmoid(v + bo);
    }
  }
}

// ---------------------------------------------------------------------------
extern "C" void kernel_launch(void* const* d_in, const int* in_sizes, int n_in,
                              void* d_out, int out_size, void* d_ws, size_t ws_size,
                              hipStream_t stream)
{
  const float* pf    = (const float*)d_in[0];
  const float* lf    = (const float*)d_in[1];
  const float* rbf   = (const float*)d_in[4];
  const float* pe_w1 = (const float*)d_in[5];
  const float* pe_b1 = (const float*)d_in[6];
  const float* pe_w2 = (const float*)d_in[7];
  const float* pe_b2 = (const float*)d_in[8];
  const float* le_w1 = (const float*)d_in[9];
  const float* le_b1 = (const float*)d_in[10];
  const float* le_w2 = (const float*)d_in[11];
  const float* le_b2 = (const float*)d_in[12];
  const float* qw = (const float*)d_in[13];
  const float* qb = (const float*)d_in[14];
  const float* kw = (const float*)d_in[15];
  const float* kb = (const float*)d_in[16];
  const float* vw = (const float*)d_in[17];
  const float* vb = (const float*)d_in[18];
  const float* rw = (const float*)d_in[19];
  const float* rb = (const float*)d_in[20];
  const float* ow = (const float*)d_in[21];
  const float* ob = (const float*)d_in[22];
  const float* ln_g = (const float*)d_in[23];
  const float* ln_b = (const float*)d_in[24];
  const float* pg_w1 = (const float*)d_in[25];
  const float* pg_b1 = (const float*)d_in[26];
  const float* pg_w2 = (const float*)d_in[27];
  const float* pg_b2 = (const float*)d_in[28];
  const float* af_w1 = (const float*)d_in[29];
  const float* af_b1 = (const float*)d_in[30];
  const float* af_w2 = (const float*)d_in[31];
  const float* af_b2 = (const float*)d_in[32];
  const float* cf_w1 = (const float*)d_in[33];
  const float* cf_b1 = (const float*)d_in[34];
  const float* cf_w2 = (const float*)d_in[35];
  const float* cf_b2 = (const float*)d_in[36];
  const float* iw1 = (const float*)d_in[37];
  const float* ib1 = (const float*)d_in[38];
  const float* iw2 = (const float*)d_in[39];
  const float* ib2 = (const float*)d_in[40];

  float* out = (float*)d_out;

  // workspace layout (floats)
  float* w = (float*)d_ws;
  size_t off = 0;
  float* prot_h = w + off; off += (size_t)PN_ * DN_;
  float* lig_h  = w + off; off += (size_t)LN_ * DN_;
  float* ph1    = w + off; off += (size_t)PN_ * DN_;
  float* lh1    = w + off; off += (size_t)LN_ * DN_;
  float* Qb     = w + off; off += (size_t)LN_ * DN_;
  float* Kt     = w + off; off += (size_t)DN_ * PN_;   // K^T; reused as pairBT
  float* Vb     = w + off; off += (size_t)PN_ * DN_;
  float* attn   = w + off; off += (size_t)LN_ * NH_ * PN_;
  float* pairA  = w + off; off += (size_t)LN_ * DN_;
  float* glog   = w + off; off += LN_;
  off = (off + 255) & ~(size_t)255;
  float* WrBF   = w + off; off += (size_t)DN_ * 64 / 2;  // 256x64 bf16
  off = (off + 255) & ~(size_t)255;
  float* rbfT   = w + off; off += (size_t)RBF_N * LP_;   // 52.4 MB

  const int PB = PN_ / 8;   // 128
  const int LB = LN_ / 8;   // 32
  const size_t smax = 8 * DN_ * sizeof(float);

  rbf_transpose<<<LP_ / 256, 256, 0, stream>>>(rbf, rbfT);
  wr_pack<<<1, 256, 0, stream>>>(iw1 + (size_t)2 * DN_ * DN_, (short*)WrBF);

  // encoder stage 1
  {
    GArgs ga;
    ga.s[0] = { pf, pe_w1, pe_b1, ph1, 20, 1, 0 };
    ga.s[1] = { lf, le_w1, le_b1, lh1, 20, 1, 0 };
    ga.s[2] = ga.s[1];
    ga.b0 = PB; ga.b1 = PB + LB;
    gemm8<<<PB + LB, 256, smax, stream>>>(ga);
  }
  // encoder stage 2
  {
    GArgs ga;
    ga.s[0] = { ph1, pe_w2, pe_b2, prot_h, DN_, 0, 0 };
    ga.s[1] = { lh1, le_w2, le_b2, lig_h, DN_, 0, 0 };
    ga.s[2] = ga.s[1];
    ga.b0 = PB; ga.b1 = PB + LB;
    gemm8<<<PB + LB, 256, smax, stream>>>(ga);
  }

  // cross-attention layers
  for (int i = 0; i < NL_; i++) {
    const size_t wo = (size_t)i * DN_ * DN_;
    {
      GArgs ga;
      ga.s[0] = { lig_h,  qw + wo, qb + i * DN_, Qb, DN_, 0, 0 };
      ga.s[1] = { prot_h, kw + wo, kb + i * DN_, Kt, DN_, 0, 1 };  // K^T
      ga.s[2] = { prot_h, vw + wo, vb + i * DN_, Vb, DN_, 0, 0 };
      ga.b0 = LB; ga.b1 = LB + PB;
      gemm8<<<LB + 2 * PB, 256, smax, stream>>>(ga);
    }
    scores_softmax_l<<<LN_, 256, 0, stream>>>(
        Qb, Kt, rbfT, rw + (size_t)i * RBF_N * NH_, rb + i * NH_, attn,
        (i == NL_ - 1) ? (out + 3 + (size_t)LN_ * PN_ * 5) : nullptr);
    attend_proj_ln<<<LN_, 256, 0, stream>>>(attn, Vb, ow + wo, ob + i * DN_,
                                            ln_g + i * DN_, ln_b + i * DN_, lig_h);
  }

  // gated pooling + heads
  gate_logits_k<<<LN_, 128, 0, stream>>>(lig_h, pg_w1, pg_b1, pg_w2, pg_b2, glog);
  pool_heads<<<1, 256, 0, stream>>>(lig_h, glog, af_w1, af_b1, af_w2, af_b2,
                                    cf_w1, cf_b1, cf_w2, cf_b2, out);

  // pair head precompute: pairA = lig_h@iw1[0:256]+ib1 (rows),
  // pairBT = (prot_h@iw1[256:512])^T via transOut (reuses Kt)
  {
    GArgs ga;
    ga.s[0] = { lig_h,  iw1,                       ib1,     pairA, DN_, 0, 0 };
    ga.s[1] = { prot_h, iw1 + (size_t)DN_ * DN_,   nullptr, Kt,    DN_, 0, 1 };
    ga.s[2] = ga.s[1];
    ga.b0 = LB; ga.b1 = LB + PB;
    gemm8<<<LB + PB, 256, smax, stream>>>(ga);
  }

  // fused pair head v4 (MFMA, double-buffered)
  pair_main4<<<(LN_ * PN_) / 128, 512, 0, stream>>>(
      pairA, Kt, rbf, (const short*)WrBF, iw2, ib2, out + 3);
}

// Round 10
// 598.053 us; speedup vs baseline: 1.4378x; 1.1958x over previous
//
#include <hip/hip_runtime.h>
#include <math.h>

#define LN_ 256      // ligand count L
#define PN_ 1024     // protein count P
#define DN_ 256      // model dim D
#define NH_ 4
#define RBF_N 50
#define NL_ 2
#define HD_ 64
#define EPSV 1e-5f
#define LP_ (LN_ * PN_)

typedef __attribute__((ext_vector_type(8))) short bf16x8;
typedef __attribute__((ext_vector_type(4))) float f32x4;

__device__ __forceinline__ float fast_sigmoid(float x){ return 1.f/(1.f+__expf(-x)); }
__device__ __forceinline__ float fast_silu(float x){ return x/(1.f+__expf(-x)); }
__device__ __forceinline__ short f2bf(float x){
  union { float f; unsigned u; } v; v.f = x;
  unsigned r = v.u + 0x7FFF + ((v.u >> 16) & 1);   // RNE
  return (short)(r >> 16);
}

// ---------------------------------------------------------------------------
// gemm8 (r4-measured form): C[row,n] = act(dot(A[row,:K], W[:,n]) + b[n]),
// 8 rows/block, 256 threads, up to 3 segments. transOut: C[n*PN_+row].
// ---------------------------------------------------------------------------
struct GSeg {
  const float* A; const float* W; const float* bias; float* C;
  int K; int act; int transOut;
};
struct GArgs { GSeg s[3]; int b0, b1; };

__global__ __launch_bounds__(256) void gemm8(GArgs ga)
{
  extern __shared__ float sA[];   // 8 * K floats
  int bid = blockIdx.x;
  int si = (bid < ga.b0) ? 0 : (bid < ga.b1 ? 1 : 2);
  int base = (si == 0) ? 0 : ((si == 1) ? ga.b0 : ga.b1);
  GSeg sg = ga.s[si];
  int row0 = (bid - base) * 8;
  int K = sg.K;
  int t = threadIdx.x;
  for (int idx = t; idx < 8 * K; idx += 256) {
    int r = idx / K, k = idx - r * K;
    sA[idx] = sg.A[(size_t)(row0 + r) * K + k];
  }
  __syncthreads();
  float acc[8];
  float bv = sg.bias ? sg.bias[t] : 0.f;
  #pragma unroll
  for (int r = 0; r < 8; r++) acc[r] = bv;
  for (int k = 0; k < K; k++) {
    float w = sg.W[(size_t)k * DN_ + t];
    #pragma unroll
    for (int r = 0; r < 8; r++) acc[r] = fmaf(sA[r * K + k], w, acc[r]);
  }
  #pragma unroll
  for (int r = 0; r < 8; r++) {
    float v = acc[r];
    if (sg.act == 1) v = fast_silu(v);
    if (sg.transOut) sg.C[(size_t)t * PN_ + row0 + r] = v;
    else             sg.C[(size_t)(row0 + r) * DN_ + t] = v;
  }
}

// ---------------------------------------------------------------------------
// rbf_bias: sL[layer][lp][h] = sum_k rbf[lp][k] * rw[layer][k][h]
// One pass over rbf (52MB). grid = LP_/256, 256 thr. Output float4/pair.
// ---------------------------------------------------------------------------
__global__ __launch_bounds__(256) void rbf_bias(
    const float* __restrict__ rbf, const float* __restrict__ rw,
    float* __restrict__ sL0, float* __restrict__ sL1)
{
  __shared__ float ld[256][RBF_N + 1];
  __shared__ float rwsh[2 * RBF_N * NH_];   // 400 floats
  int t = threadIdx.x;
  size_t base = (size_t)blockIdx.x << 8;
  const float* src = rbf + base * RBF_N;
  for (int i = 0; i < RBF_N; i++) {
    int fl = i * 256 + t;
    int row = fl / RBF_N, colk = fl - row * RBF_N;
    ld[row][colk] = src[fl];
  }
  for (int i = t; i < 2 * RBF_N * NH_; i += 256) rwsh[i] = rw[i];
  __syncthreads();
  #pragma unroll
  for (int layer = 0; layer < 2; layer++) {
    f32x4 acc = {0.f, 0.f, 0.f, 0.f};
    const float* rwl = rwsh + layer * RBF_N * NH_;
    #pragma unroll 10
    for (int k = 0; k < RBF_N; k++) {
      float rv = ld[t][k];
      acc[0] = fmaf(rv, rwl[k * 4 + 0], acc[0]);
      acc[1] = fmaf(rv, rwl[k * 4 + 1], acc[1]);
      acc[2] = fmaf(rv, rwl[k * 4 + 2], acc[2]);
      acc[3] = fmaf(rv, rwl[k * 4 + 3], acc[3]);
    }
    float* dst = (layer == 0 ? sL0 : sL1) + (base + t) * 4;
    *(f32x4*)dst = acc;
  }
}

// ---------------------------------------------------------------------------
// pack Wr into fragment-ready bf16 [d][64] (k>=50 zero).
// ---------------------------------------------------------------------------
__global__ __launch_bounds__(256) void wr_pack(
    const float* __restrict__ Wr, short* __restrict__ WT)
{
  int d = threadIdx.x;
  for (int k = 0; k < 64; k++)
    WT[d * 64 + k] = (k < RBF_N) ? f2bf(Wr[k * DN_ + d]) : (short)0;
}

// ---------------------------------------------------------------------------
// layer_fused: scores(+s2 bias)+softmax -> attend (attn in LDS) -> proj ->
// residual -> LN. grid = L blocks, 512 threads (8 waves).
// Phase1: thread t covers p={t, t+512}. Phase2: 2 p-groups x 256 (h,d).
// ---------------------------------------------------------------------------
__global__ __launch_bounds__(512) void layer_fused(
    const float* __restrict__ Q, const float* __restrict__ Kt,
    const float* __restrict__ V, const float* __restrict__ s2,
    const float* __restrict__ rbp, const float* __restrict__ ow,
    const float* __restrict__ ob, const float* __restrict__ g,
    const float* __restrict__ bb, float* __restrict__ lig,
    float* __restrict__ amean)
{
  __shared__ float qs[DN_];
  __shared__ float asm_[NH_][PN_];     // 16 KB attn weights
  __shared__ float redm[NH_][8], reds[NH_][8];
  __shared__ float part[2][256];
  __shared__ float as_[DN_];
  __shared__ float red[8];

  int l = blockIdx.x, t = threadIdx.x, lane = t & 63, wv = t >> 6;
  if (t < DN_) qs[t] = Q[(size_t)l * DN_ + t];
  __syncthreads();

  // ---- phase 1: scores ----
  float sc[NH_][2];
  #pragma unroll
  for (int i = 0; i < 2; i++) {
    int p = t + (i << 9);
    f32x4 s2v = *(const f32x4*)(s2 + ((size_t)(l << 10) + p) * 4);
    #pragma unroll
    for (int h = 0; h < NH_; h++) {
      const float* kp = Kt + ((size_t)(h << 6) << 10) + p;
      float a = 0.f;
      #pragma unroll 8
      for (int d = 0; d < HD_; d++) a = fmaf(qs[(h << 6) + d], kp[(size_t)d << 10], a);
      sc[h][i] = a * 0.125f + s2v[h] + rbp[h];
    }
  }

  // softmax over 1024 p (8 waves)
  #pragma unroll
  for (int h = 0; h < NH_; h++) {
    float m = fmaxf(sc[h][0], sc[h][1]);
    for (int o = 32; o > 0; o >>= 1) m = fmaxf(m, __shfl_xor(m, o));
    if (lane == 0) redm[h][wv] = m;
  }
  __syncthreads();
  float mh[NH_];
  #pragma unroll
  for (int h = 0; h < NH_; h++) {
    float m = redm[h][0];
    #pragma unroll
    for (int i = 1; i < 8; i++) m = fmaxf(m, redm[h][i]);
    mh[h] = m;
  }
  float e[NH_][2];
  #pragma unroll
  for (int h = 0; h < NH_; h++) {
    e[h][0] = __expf(sc[h][0] - mh[h]);
    e[h][1] = __expf(sc[h][1] - mh[h]);
    float s = e[h][0] + e[h][1];
    for (int o = 32; o > 0; o >>= 1) s += __shfl_xor(s, o);
    if (lane == 0) reds[h][wv] = s;
  }
  __syncthreads();
  float am0 = 0.f, am1 = 0.f;
  #pragma unroll
  for (int h = 0; h < NH_; h++) {
    float s = reds[h][0];
    #pragma unroll
    for (int i = 1; i < 8; i++) s += reds[h][i];
    float inv = 1.f / s;
    float a0 = e[h][0] * inv, a1 = e[h][1] * inv;
    asm_[h][t] = a0;
    asm_[h][t + 512] = a1;
    am0 += a0; am1 += a1;
  }
  if (amean) {
    amean[((size_t)l << 10) + t] = am0 * 0.25f;
    amean[((size_t)l << 10) + t + 512] = am1 * 0.25f;
  }
  __syncthreads();

  // ---- phase 2: attend (2 p-groups x 256 (h,d) combos) ----
  {
    int g2 = t >> 8, c = t & 255;       // h = c>>6 uniform per wave
    const float* ap = asm_[c >> 6];
    float acc = 0.f;
    int pbeg = g2 << 9;
    #pragma unroll 8
    for (int p = pbeg; p < pbeg + 512; p++)
      acc = fmaf(ap[p], V[((size_t)p << 8) + c], acc);
    part[g2][c] = acc;
  }
  __syncthreads();
  if (t < 256) as_[t] = part[0][t] + part[1][t];
  __syncthreads();

  // ---- phase 3: proj + residual + LN (first 256 threads) ----
  float x = 0.f;
  if (t < 256) {
    float acc2 = ob[t];
    #pragma unroll 4
    for (int k = 0; k < DN_; k++) acc2 = fmaf(as_[k], ow[(size_t)(k << 8) + t], acc2);
    x = lig[((size_t)l << 8) + t] + acc2;
  }
  float sm = x;
  for (int o = 32; o > 0; o >>= 1) sm += __shfl_xor(sm, o);
  if (t < 256 && lane == 0) red[wv] = sm;
  __syncthreads();
  float mu = (red[0] + red[1] + red[2] + red[3]) * (1.f / DN_);
  float dx = x - mu;
  float v = dx * dx;
  for (int o = 32; o > 0; o >>= 1) v += __shfl_xor(v, o);
  if (t < 256 && lane == 0) red[4 + wv] = v;
  __syncthreads();
  if (t < 256) {
    float var = (red[4] + red[5] + red[6] + red[7]) * (1.f / DN_);
    lig[((size_t)l << 8) + t] = dx * (1.f / sqrtf(var + EPSV)) * g[t] + bb[t];
  }
}

// ---------------------------------------------------------------------------
// gate logits. grid = L, 128 threads.
// ---------------------------------------------------------------------------
__global__ __launch_bounds__(128) void gate_logits_k(
    const float* __restrict__ lig, const float* __restrict__ w1,
    const float* __restrict__ b1, const float* __restrict__ w2,
    const float* __restrict__ b2, float* __restrict__ glog)
{
  int l = blockIdx.x, n = threadIdx.x, lane = n & 63, wv = n >> 6;
  __shared__ float ls[DN_];
  __shared__ float red[2];
  ls[n] = lig[(size_t)l * DN_ + n];
  ls[n + 128] = lig[(size_t)l * DN_ + n + 128];
  __syncthreads();
  float acc = b1[n];
  #pragma unroll 4
  for (int k = 0; k < DN_; k++) acc = fmaf(ls[k], w1[k * 128 + n], acc);
  float part = tanhf(acc) * w2[n];
  for (int o = 32; o > 0; o >>= 1) part += __shfl_xor(part, o);
  if (lane == 0) red[wv] = part;
  __syncthreads();
  if (n == 0) glog[l] = red[0] + red[1] + b2[0];
}

// ---------------------------------------------------------------------------
// gate softmax + pooled repr + heads. 1 block, 256 threads.
// ---------------------------------------------------------------------------
__global__ __launch_bounds__(256) void pool_heads(
    const float* __restrict__ lig, const float* __restrict__ glog,
    const float* __restrict__ afw1, const float* __restrict__ afb1,
    const float* __restrict__ afw2, const float* __restrict__ afb2,
    const float* __restrict__ cfw1, const float* __restrict__ cfb1,
    const float* __restrict__ cfw2, const float* __restrict__ cfb2,
    float* __restrict__ out)
{
  __shared__ float wsh[LN_];
  __shared__ float cr[DN_];
  __shared__ float h1s[DN_];
  __shared__ float h2s[128];
  __shared__ float red[8];
  int t = threadIdx.x, lane = t & 63, wv = t >> 6;
  float x = glog[t];
  float m = x;
  for (int o = 32; o > 0; o >>= 1) m = fmaxf(m, __shfl_xor(m, o));
  if (lane == 0) red[wv] = m;
  __syncthreads();
  m = fmaxf(fmaxf(red[0], red[1]), fmaxf(red[2], red[3]));
  float e = __expf(x - m);
  float s = e;
  for (int o = 32; o > 0; o >>= 1) s += __shfl_xor(s, o);
  if (lane == 0) red[4 + wv] = s;
  __syncthreads();
  s = red[4] + red[5] + red[6] + red[7];
  wsh[t] = e / s;
  __syncthreads();
  float acc = 0.f;
  #pragma unroll 4
  for (int l2 = 0; l2 < LN_; l2++) acc = fmaf(wsh[l2], lig[(size_t)l2 * DN_ + t], acc);
  cr[t] = acc;
  __syncthreads();
  float a = afb1[t];
  #pragma unroll 4
  for (int d = 0; d < DN_; d++) a = fmaf(cr[d], afw1[d * DN_ + t], a);
  h1s[t] = fast_silu(a);
  if (t < 128) {
    float c = cfb1[t];
    #pragma unroll 4
    for (int d = 0; d < DN_; d++) c = fmaf(cr[d], cfw1[d * 128 + t], c);
    h2s[t] = fast_silu(c);
  }
  __syncthreads();
  float pp = h1s[t] * afw2[t];
  for (int o = 32; o > 0; o >>= 1) pp += __shfl_xor(pp, o);
  if (lane == 0) red[wv] = pp;
  float cp = (t < 128) ? h2s[t] * cfw2[t] : 0.f;
  for (int o = 32; o > 0; o >>= 1) cp += __shfl_xor(cp, o);
  if (lane == 0) red[4 + wv] = cp;
  __syncthreads();
  if (t == 0) {
    float pkd = red[0] + red[1] + red[2] + red[3] + afb2[0];
    float cl  = red[4] + red[5] + red[6] + red[7] + cfb2[0];
    float conf = fast_sigmoid(cl);
    out[0] = pkd * conf;
    out[1] = pkd;
    out[2] = conf;
  }
}

// ---------------------------------------------------------------------------
// pair head v4 (r8-measured: 101us): MFMA + dbuf sBT union + T14 async-stage.
// block = 1 l x 128 p, 512 thr = 8 waves. grid = 2048. LDS 24.6KB.
// ---------------------------------------------------------------------------
#define RSTR 72
#define BTP2 133
union PairSMem {
  short R[128 * RSTR];
  float B[2][16 * BTP2];
};
__global__ __launch_bounds__(512, 6) void pair_main4(
    const float* __restrict__ A, const float* __restrict__ BT,
    const float* __restrict__ rbf, const short* __restrict__ WT,
    const float* __restrict__ w2, const float* __restrict__ ib2,
    float* __restrict__ imap)
{
  __shared__ PairSMem u;
  __shared__ float sw2[DN_ * 5];
  __shared__ float sAl[DN_];

  int t = threadIdx.x;
  int lane = t & 63, wid = t >> 6;
  int bid = blockIdx.x;
  int l = bid >> 3;
  int p0 = (bid & 7) << 7;

  {
    unsigned* rz = (unsigned*)u.R;
    #pragma unroll
    for (int i = 0; i < 9; i++) rz[t + i * 512] = 0u;
  }
  __syncthreads();
  {
    const float* src = rbf + ((size_t)(l << 10) + p0) * RBF_N;
    #pragma unroll
    for (int i = 0; i < 13; i++) {
      int idx = t + i * 512;
      if (idx < 128 * RBF_N) {
        int row = idx / RBF_N, k = idx - row * RBF_N;
        u.R[row * RSTR + k] = f2bf(src[idx]);
      }
    }
  }
  for (int i = t; i < DN_ * 5; i += 512) sw2[i] = w2[i];
  if (t < DN_) sAl[t] = A[((size_t)l << 8) + t];
  __syncthreads();

  int m = lane & 15, gq = lane >> 4;
  bf16x8 a0 = *(const bf16x8*)&u.R[(wid * 16 + m) * RSTR + 0 + gq * 8];
  bf16x8 a1 = *(const bf16x8*)&u.R[(wid * 16 + m) * RSTR + 32 + gq * 8];
  __syncthreads();

  int srow = t >> 7, scol = t & 127;
  #pragma unroll
  for (int i = 0; i < 4; i++)
    u.B[0][(srow + 4 * i) * BTP2 + scol] =
        BT[(size_t)(srow + 4 * i) * PN_ + p0 + scol];
  __syncthreads();

  float acc5[4][5];
  #pragma unroll
  for (int r = 0; r < 4; r++)
    #pragma unroll
    for (int o = 0; o < 5; o++) acc5[r][o] = 0.f;

  int cur = 0;
  for (int nt = 0; nt < 16; nt++) {
    float ld0 = 0.f, ld1 = 0.f, ld2 = 0.f, ld3 = 0.f;
    if (nt < 15) {
      const float* bsrc = BT + (size_t)((nt + 1) * 16 + srow) * PN_ + p0 + scol;
      ld0 = bsrc[0];
      ld1 = bsrc[(size_t)4 * PN_];
      ld2 = bsrc[(size_t)8 * PN_];
      ld3 = bsrc[(size_t)12 * PN_];
    }
    int n = nt * 16 + m;
    bf16x8 b0 = *(const bf16x8*)&WT[n * 64 + gq * 8];
    bf16x8 b1 = *(const bf16x8*)&WT[n * 64 + 32 + gq * 8];
    f32x4 acc = {0.f, 0.f, 0.f, 0.f};
    acc = __builtin_amdgcn_mfma_f32_16x16x32_bf16(a0, b0, acc, 0, 0, 0);
    acc = __builtin_amdgcn_mfma_f32_16x16x32_bf16(a1, b1, acc, 0, 0, 0);
    float bA = sAl[n];
    const float* bp = &u.B[cur][m * BTP2 + wid * 16 + gq * 4];
    #pragma unroll
    for (int r = 0; r < 4; r++) {
      float h = acc[r] + bA + bp[r];
      float sh = fast_silu(h);
      #pragma unroll
      for (int o = 0; o < 5; o++)
        acc5[r][o] = fmaf(sh, sw2[n * 5 + o], acc5[r][o]);
    }
    __syncthreads();
    if (nt < 15) {
      float* bd = &u.B[cur ^ 1][srow * BTP2 + scol];
      bd[0 * 4 * BTP2] = ld0;
      bd[1 * 4 * BTP2] = ld1;
      bd[2 * 4 * BTP2] = ld2;
      bd[3 * 4 * BTP2] = ld3;
      __syncthreads();
      cur ^= 1;
    }
  }

  #pragma unroll
  for (int r = 0; r < 4; r++)
    #pragma unroll
    for (int o = 0; o < 5; o++) {
      float v = acc5[r][o];
      v += __shfl_xor(v, 1);
      v += __shfl_xor(v, 2);
      v += __shfl_xor(v, 4);
      v += __shfl_xor(v, 8);
      acc5[r][o] = v;
    }

  if (m < 5) {
    float bo = ib2[m];
    #pragma unroll
    for (int r = 0; r < 4; r++) {
      float v = 0.f;
      #pragma unroll
      for (int o = 0; o < 5; o++) if (m == o) v = acc5[r][o];
      int p = p0 + wid * 16 + gq * 4 + r;
      imap[((size_t)(l << 10) + p) * 5 + m] = fast_sigmoid(v + bo);
    }
  }
}

// ---------------------------------------------------------------------------
extern "C" void kernel_launch(void* const* d_in, const int* in_sizes, int n_in,
                              void* d_out, int out_size, void* d_ws, size_t ws_size,
                              hipStream_t stream)
{
  const float* pf    = (const float*)d_in[0];
  const float* lf    = (const float*)d_in[1];
  const float* rbf   = (const float*)d_in[4];
  const float* pe_w1 = (const float*)d_in[5];
  const float* pe_b1 = (const float*)d_in[6];
  const float* pe_w2 = (const float*)d_in[7];
  const float* pe_b2 = (const float*)d_in[8];
  const float* le_w1 = (const float*)d_in[9];
  const float* le_b1 = (const float*)d_in[10];
  const float* le_w2 = (const float*)d_in[11];
  const float* le_b2 = (const float*)d_in[12];
  const float* qw = (const float*)d_in[13];
  const float* qb = (const float*)d_in[14];
  const float* kw = (const float*)d_in[15];
  const float* kb = (const float*)d_in[16];
  const float* vw = (const float*)d_in[17];
  const float* vb = (const float*)d_in[18];
  const float* rw = (const float*)d_in[19];
  const float* rb = (const float*)d_in[20];
  const float* ow = (const float*)d_in[21];
  const float* ob = (const float*)d_in[22];
  const float* ln_g = (const float*)d_in[23];
  const float* ln_b = (const float*)d_in[24];
  const float* pg_w1 = (const float*)d_in[25];
  const float* pg_b1 = (const float*)d_in[26];
  const float* pg_w2 = (const float*)d_in[27];
  const float* pg_b2 = (const float*)d_in[28];
  const float* af_w1 = (const float*)d_in[29];
  const float* af_b1 = (const float*)d_in[30];
  const float* af_w2 = (const float*)d_in[31];
  const float* af_b2 = (const float*)d_in[32];
  const float* cf_w1 = (const float*)d_in[33];
  const float* cf_b1 = (const float*)d_in[34];
  const float* cf_w2 = (const float*)d_in[35];
  const float* cf_b2 = (const float*)d_in[36];
  const float* iw1 = (const float*)d_in[37];
  const float* ib1 = (const float*)d_in[38];
  const float* iw2 = (const float*)d_in[39];
  const float* ib2 = (const float*)d_in[40];

  float* out = (float*)d_out;

  // workspace layout (floats)
  float* w = (float*)d_ws;
  size_t off = 0;
  float* prot_h = w + off; off += (size_t)PN_ * DN_;
  float* lig_h  = w + off; off += (size_t)LN_ * DN_;
  float* ph1    = w + off; off += (size_t)PN_ * DN_;
  float* lh1    = w + off; off += (size_t)LN_ * DN_;
  float* Qb     = w + off; off += (size_t)LN_ * DN_;
  float* Kt     = w + off; off += (size_t)DN_ * PN_;   // K^T; reused as pairBT
  float* Vb     = w + off; off += (size_t)PN_ * DN_;
  float* pairA  = w + off; off += (size_t)LN_ * DN_;
  float* glog   = w + off; off += LN_;
  off = (off + 255) & ~(size_t)255;
  float* WrBF   = w + off; off += (size_t)DN_ * 64 / 2;  // 256x64 bf16
  off = (off + 255) & ~(size_t)255;
  float* sL0    = w + off; off += (size_t)LP_ * NH_;     // 4 MB rbf bias layer 0
  float* sL1    = w + off; off += (size_t)LP_ * NH_;     // 4 MB rbf bias layer 1

  const int PB = PN_ / 8;   // 128
  const int LB = LN_ / 8;   // 32
  const size_t smax = 8 * DN_ * sizeof(float);

  rbf_bias<<<LP_ / 256, 256, 0, stream>>>(rbf, rw, sL0, sL1);
  wr_pack<<<1, 256, 0, stream>>>(iw1 + (size_t)2 * DN_ * DN_, (short*)WrBF);

  // encoder stage 1
  {
    GArgs ga;
    ga.s[0] = { pf, pe_w1, pe_b1, ph1, 20, 1, 0 };
    ga.s[1] = { lf, le_w1, le_b1, lh1, 20, 1, 0 };
    ga.s[2] = ga.s[1];
    ga.b0 = PB; ga.b1 = PB + LB;
    gemm8<<<PB + LB, 256, smax, stream>>>(ga);
  }
  // encoder stage 2
  {
    GArgs ga;
    ga.s[0] = { ph1, pe_w2, pe_b2, prot_h, DN_, 0, 0 };
    ga.s[1] = { lh1, le_w2, le_b2, lig_h, DN_, 0, 0 };
    ga.s[2] = ga.s[1];
    ga.b0 = PB; ga.b1 = PB + LB;
    gemm8<<<PB + LB, 256, smax, stream>>>(ga);
  }

  // cross-attention layers
  for (int i = 0; i < NL_; i++) {
    const size_t wo = (size_t)i * DN_ * DN_;
    {
      GArgs ga;
      ga.s[0] = { lig_h,  qw + wo, qb + i * DN_, Qb, DN_, 0, 0 };
      ga.s[1] = { prot_h, kw + wo, kb + i * DN_, Kt, DN_, 0, 1 };  // K^T
      ga.s[2] = { prot_h, vw + wo, vb + i * DN_, Vb, DN_, 0, 0 };
      ga.b0 = LB; ga.b1 = LB + PB;
      gemm8<<<LB + 2 * PB, 256, smax, stream>>>(ga);
    }
    layer_fused<<<LN_, 512, 0, stream>>>(
        Qb, Kt, Vb, (i == 0) ? sL0 : sL1, rb + i * NH_,
        ow + wo, ob + i * DN_, ln_g + i * DN_, ln_b + i * DN_, lig_h,
        (i == NL_ - 1) ? (out + 3 + (size_t)LN_ * PN_ * 5) : nullptr);
  }

  // gated pooling + heads
  gate_logits_k<<<LN_, 128, 0, stream>>>(lig_h, pg_w1, pg_b1, pg_w2, pg_b2, glog);
  pool_heads<<<1, 256, 0, stream>>>(lig_h, glog, af_w1, af_b1, af_w2, af_b2,
                                    cf_w1, cf_b1, cf_w2, cf_b2, out);

  // pair head precompute: pairA = lig_h@iw1[0:256]+ib1 (rows),
  // pairBT = (prot_h@iw1[256:512])^T via transOut (reuses Kt)
  {
    GArgs ga;
    ga.s[0] = { lig_h,  iw1,                       ib1,     pairA, DN_, 0, 0 };
    ga.s[1] = { prot_h, iw1 + (size_t)DN_ * DN_,   nullptr, Kt,    DN_, 0, 1 };
    ga.s[2] = ga.s[1];
    ga.b0 = LB; ga.b1 = LB + PB;
    gemm8<<<LB + PB, 256, smax, stream>>>(ga);
  }

  // fused pair head v4 (MFMA, double-buffered)
  pair_main4<<<(LN_ * PN_) / 128, 512, 0, stream>>>(
      pairA, Kt, rbf, (const short*)WrBF, iw2, ib2, out + 3);
}